// Round 4
// baseline (201.118 us; speedup 1.0000x reference)
//
#include <hip/hip_runtime.h>
#include <hip/hip_bf16.h>

#define TB 8
#define TT 2048
#define TC 1024
#define TH 64

typedef __bf16 bf16;
typedef __bf16 bf16x4 __attribute__((ext_vector_type(4)));
typedef __bf16 bf16x8 __attribute__((ext_vector_type(8)));
typedef float  f32x4  __attribute__((ext_vector_type(4)));

// softmax scale folded with log2(e): attn uses exp2 instead of exp
constexpr float QSCALE = 0.125f * 1.44269504088896340736f;

// ---------------------------------------------------------------------------
// Kernel 1: transpose + cast weights: w_{q,k,v}[1024][64] fp32 -> wT[3][64][1024] bf16
// ---------------------------------------------------------------------------
__global__ void prep_wT(const float* __restrict__ wq, const float* __restrict__ wk,
                        const float* __restrict__ wv, bf16* __restrict__ wT) {
    int idx = blockIdx.x * blockDim.x + threadIdx.x;
    if (idx >= 3 * TH * TC) return;
    int wsel = idx / (TH * TC);
    int rem  = idx % (TH * TC);
    int c = rem / TH;
    int h = rem % TH;
    const float* w = (wsel == 0) ? wq : (wsel == 1) ? wk : wv;
    wT[(size_t)wsel * TH * TC + (size_t)h * TC + c] = (bf16)w[(size_t)c * TH + h];
}

// ---------------------------------------------------------------------------
// Kernel 2: QKV projection, output-split. One wave = 16 rows x ONE of {Q,K,V}
// (64 cols), full K=1024. 3072 single-wave blocks. Register rings sized to
// FIT (prev rounds spilled: VGPR=96 < ~180 live -> scratch round-trips).
// __launch_bounds__(64,2) grants 256 VGPRs; ~150 live -> no spill.
// ---------------------------------------------------------------------------
__launch_bounds__(64, 2)
__global__ void proj3(const float* __restrict__ x, const bf16* __restrict__ wT,
                      bf16* __restrict__ Q, bf16* __restrict__ K, bf16* __restrict__ V) {
    const int lane = threadIdx.x;
    const int quad = lane >> 4, l16 = lane & 15;
    const int wsel = blockIdx.x % 3;      // trio with same rt adjacent -> x L2/L3 reuse
    const int rt   = blockIdx.x / 3;
    const int m0   = rt * 16;

    const float* xp = x  + (size_t)(m0 + l16) * TC + quad * 8;
    const bf16*  wp = wT + (size_t)wsel * TH * TC + quad * 8;

    f32x4 acc[4];
#pragma unroll
    for (int g = 0; g < 4; g++) acc[g] = f32x4{0.f, 0.f, 0.f, 0.f};

    // x ring depth 6 (48 VGPR), B ring depth 4 (64 VGPR)
    float4 xa[6][2];
#pragma unroll
    for (int p = 0; p < 6; p++) {
        xa[p][0] = ((const float4*)(xp + p * 32))[0];
        xa[p][1] = ((const float4*)(xp + p * 32))[1];
    }
    bf16x8 bb[4][4];
#pragma unroll
    for (int p = 0; p < 4; p++)
#pragma unroll
        for (int g = 0; g < 4; g++)
            bb[p][g] = *(const bf16x8*)(wp + (size_t)(g * 16 + l16) * TC + p * 32);

#pragma unroll
    for (int kc = 0; kc < 32; kc++) {
        const int xs = kc % 6, bs = kc & 3;
        bf16x8 af;
        af[0] = (bf16)xa[xs][0].x; af[1] = (bf16)xa[xs][0].y;
        af[2] = (bf16)xa[xs][0].z; af[3] = (bf16)xa[xs][0].w;
        af[4] = (bf16)xa[xs][1].x; af[5] = (bf16)xa[xs][1].y;
        af[6] = (bf16)xa[xs][1].z; af[7] = (bf16)xa[xs][1].w;
#pragma unroll
        for (int g = 0; g < 4; g++)
            acc[g] = __builtin_amdgcn_mfma_f32_16x16x32_bf16(af, bb[bs][g], acc[g], 0, 0, 0);
        if (kc + 6 < 32) {
            xa[xs][0] = ((const float4*)(xp + (kc + 6) * 32))[0];
            xa[xs][1] = ((const float4*)(xp + (kc + 6) * 32))[1];
        }
        if (kc + 4 < 32) {
#pragma unroll
            for (int g = 0; g < 4; g++)
                bb[bs][g] = *(const bf16x8*)(wp + (size_t)(g * 16 + l16) * TC + (kc + 4) * 32);
        }
    }

    // epilogue: C layout row = quad*4+r, col = g*16+l16. V stored row-major.
    bf16* dst = (wsel == 0) ? Q : (wsel == 1) ? K : V;
    const float sc = (wsel == 0) ? QSCALE : 1.0f;
    const int mrow = m0 + quad * 4;
#pragma unroll
    for (int g = 0; g < 4; g++) {
        int col = g * 16 + l16;
#pragma unroll
        for (int r = 0; r < 4; r++)
            dst[(size_t)(mrow + r) * TH + col] = (bf16)(acc[g][r] * sc);
    }
}

// ---------------------------------------------------------------------------
// Kernel 2b: V [B*T][64] -> VT [B][64][T]. Gather-read (L2-hot), coalesced store.
// ---------------------------------------------------------------------------
__launch_bounds__(256)
__global__ void vtrans(const bf16* __restrict__ V, bf16* __restrict__ VT) {
    const int gid = blockIdx.x * 256 + threadIdx.x;
    const int ts = gid & 255;          // 8-elem t segment
    const int h  = (gid >> 8) & 63;
    const int b  = gid >> 14;
    const bf16* vp = V + ((size_t)b * TT + ts * 8) * TH + h;
    bf16x8 o;
#pragma unroll
    for (int i = 0; i < 8; i++) o[i] = vp[(size_t)i * TH];
    *(bf16x8*)(VT + ((size_t)b * TH + h) * TT + ts * 8) = o;
}

// ---------------------------------------------------------------------------
// Kernel 3: causal flash attention (unchanged).
// ---------------------------------------------------------------------------
#define LDP 72
#define NW 4

__launch_bounds__(256)
__global__ void attn(const bf16* __restrict__ Q, const bf16* __restrict__ K,
                     const bf16* __restrict__ VT, float* __restrict__ out) {
    __shared__ __align__(16) union SM {
        bf16 P[NW][2][16][LDP];
        struct { float O[NW][16][68]; float M[NW][16]; float L[NW][16]; } mg;
    } sm;

    const int tid  = threadIdx.x;
    const int wv   = tid >> 6;
    const int lane = tid & 63;
    const int quad = lane >> 4, l16 = lane & 15;
    const int b  = blockIdx.x & 7;
    const int rt = 127 - (blockIdx.x >> 3);
    const int q0 = rt * 16;
    const int ktmax = rt >> 2;

    const bf16* Qb = Q  + (size_t)b * TT * TH;
    const bf16* Kb = K  + (size_t)b * TT * TH;
    const bf16* Vb = VT + (size_t)b * TH * TT;

    bf16x8 bq0, bq1;
    {
        const bf16* qp = Qb + (size_t)(q0 + l16) * TH + quad * 8;
        bq0 = *(const bf16x8*)qp;
        bq1 = *(const bf16x8*)(qp + 32);
    }

    f32x4 accO[4];
#pragma unroll
    for (int g = 0; g < 4; g++) accO[g] = f32x4{0.f, 0.f, 0.f, 0.f};
    float mI = -1e30f, lI = 0.f;

    int nit = 0;
    for (int kt = wv; kt <= ktmax; kt += NW, nit++) {
        const int k0 = kt * 64;

        f32x4 s[4];
#pragma unroll
        for (int g = 0; g < 4; g++) {
            const bf16* kp = Kb + (size_t)(k0 + g * 16 + l16) * TH + quad * 8;
            bf16x8 ka0 = *(const bf16x8*)kp;
            bf16x8 ka1 = *(const bf16x8*)(kp + 32);
            f32x4 t = f32x4{0.f, 0.f, 0.f, 0.f};
            t = __builtin_amdgcn_mfma_f32_16x16x32_bf16(ka0, bq0, t, 0, 0, 0);
            t = __builtin_amdgcn_mfma_f32_16x16x32_bf16(ka1, bq1, t, 0, 0, 0);
            s[g] = t;
        }

        if (kt == ktmax) {
            const int qrel = ((rt & 3) << 4) + l16;
#pragma unroll
            for (int g = 0; g < 4; g++)
#pragma unroll
                for (int r = 0; r < 4; r++)
                    if (g * 16 + quad * 4 + r > qrel) s[g][r] = -3.0e38f;
        }

        float mx = s[0][0];
#pragma unroll
        for (int g = 0; g < 4; g++)
#pragma unroll
            for (int r = 0; r < 4; r++) mx = fmaxf(mx, s[g][r]);
        mx = fmaxf(mx, __shfl_xor(mx, 16));
        mx = fmaxf(mx, __shfl_xor(mx, 32));
        float mnew  = fmaxf(mI, mx);
        float alpha = exp2f(mI - mnew);
        mI = mnew;
        float rs = 0.f;
#pragma unroll
        for (int g = 0; g < 4; g++)
#pragma unroll
            for (int r = 0; r < 4; r++) {
                float p = exp2f(s[g][r] - mnew);
                s[g][r] = p;
                rs += p;
            }
        rs += __shfl_xor(rs, 16);
        rs += __shfl_xor(rs, 32);
        lI = lI * alpha + rs;

        float arow[4];
#pragma unroll
        for (int r = 0; r < 4; r++) arow[r] = __shfl(alpha, quad * 4 + r);
#pragma unroll
        for (int g = 0; g < 4; g++)
#pragma unroll
            for (int r = 0; r < 4; r++) accO[g][r] *= arow[r];

        const int par = nit & 1;
#pragma unroll
        for (int g = 0; g < 4; g++) {
            bf16x4 pk;
            pk[0] = (bf16)s[g][0]; pk[1] = (bf16)s[g][1];
            pk[2] = (bf16)s[g][2]; pk[3] = (bf16)s[g][3];
            *(bf16x4*)(&sm.P[wv][par][l16][g * 16 + quad * 4]) = pk;
        }
        __threadfence_block();

#pragma unroll
        for (int c = 0; c < 2; c++) {
            bf16x8 ap = *(const bf16x8*)(&sm.P[wv][par][l16][c * 32 + quad * 8]);
#pragma unroll
            for (int g = 0; g < 4; g++) {
                const bf16* vp = Vb + (size_t)(g * 16 + l16) * TT + k0 + c * 32 + quad * 8;
                bf16x8 bv = *(const bf16x8*)vp;
                accO[g] = __builtin_amdgcn_mfma_f32_16x16x32_bf16(ap, bv, accO[g], 0, 0, 0);
            }
        }
    }

    __syncthreads();
#pragma unroll
    for (int g = 0; g < 4; g++)
#pragma unroll
        for (int r = 0; r < 4; r++)
            sm.mg.O[wv][quad * 4 + r][g * 16 + l16] = accO[g][r];
    if (lane < 16) {
        sm.mg.M[wv][lane] = mI;
        sm.mg.L[wv][lane] = lI;
    }
    __syncthreads();

    {
        const int q = tid >> 4;
        const int h = (tid & 15) * 4;
        float gm = sm.mg.M[0][q];
#pragma unroll
        for (int w = 1; w < NW; w++) gm = fmaxf(gm, sm.mg.M[w][q]);
        float denom = 0.f, o0 = 0.f, o1 = 0.f, o2 = 0.f, o3 = 0.f;
#pragma unroll
        for (int w = 0; w < NW; w++) {
            float sc = exp2f(sm.mg.M[w][q] - gm);
            denom += sm.mg.L[w][q] * sc;
            o0 += sm.mg.O[w][q][h + 0] * sc;
            o1 += sm.mg.O[w][q][h + 1] * sc;
            o2 += sm.mg.O[w][q][h + 2] * sc;
            o3 += sm.mg.O[w][q][h + 3] * sc;
        }
        float inv = 1.f / denom;
        float4 res = make_float4(o0 * inv, o1 * inv, o2 * inv, o3 * inv);
        *(float4*)(out + ((size_t)b * TT + q0 + q) * TH + h) = res;
    }
}

// ---------------------------------------------------------------------------
extern "C" void kernel_launch(void* const* d_in, const int* in_sizes, int n_in,
                              void* d_out, int out_size, void* d_ws, size_t ws_size,
                              hipStream_t stream) {
    const float* x  = (const float*)d_in[0];
    const float* wq = (const float*)d_in[1];
    const float* wk = (const float*)d_in[2];
    const float* wv = (const float*)d_in[3];

    char* ws = (char*)d_ws;
    bf16*  wT = (bf16*)(ws);                        // 393216 B
    bf16*  Q  = (bf16*)(ws + 393216);               // 2 MB
    bf16*  K  = (bf16*)(ws + 2490368);              // 2 MB
    bf16*  VT = (bf16*)(ws + 4587520);              // 2 MB
    bf16*  V  = (bf16*)(ws + 6684672);              // 2 MB (row-major staging)
    float* out = (float*)d_out;

    hipLaunchKernelGGL(prep_wT, dim3(768), dim3(256), 0, stream, wq, wk, wv, wT);
    hipLaunchKernelGGL(proj3, dim3(3072), dim3(64), 0, stream, x, wT, Q, K, V);
    hipLaunchKernelGGL(vtrans, dim3(512), dim3(256), 0, stream, V, VT);
    hipLaunchKernelGGL(attn, dim3(TB * 128), dim3(256), 0, stream, Q, K, VT, out);
}

// Round 5
// 196.694 us; speedup vs baseline: 1.0225x; 1.0225x over previous
//
#include <hip/hip_runtime.h>
#include <hip/hip_bf16.h>
#include <cstdint>

#define TB 8
#define TT 2048
#define TC 1024
#define TH 64

typedef __bf16 bf16;
typedef __bf16 bf16x4 __attribute__((ext_vector_type(4)));
typedef __bf16 bf16x8 __attribute__((ext_vector_type(8)));
typedef float  f32x4  __attribute__((ext_vector_type(4)));

// softmax scale folded with log2(e): attn uses exp2 instead of exp
constexpr float QSCALE = 0.125f * 1.44269504088896340736f;

// ---------------------------------------------------------------------------
// Kernel 1: transpose + cast weights: w_{q,k,v}[1024][64] fp32 -> wT[3][64][1024] bf16
// ---------------------------------------------------------------------------
__global__ void prep_wT(const float* __restrict__ wq, const float* __restrict__ wk,
                        const float* __restrict__ wv, bf16* __restrict__ wT) {
    int idx = blockIdx.x * blockDim.x + threadIdx.x;
    if (idx >= 3 * TH * TC) return;
    int wsel = idx / (TH * TC);
    int rem  = idx % (TH * TC);
    int c = rem / TH;
    int h = rem % TH;
    const float* w = (wsel == 0) ? wq : (wsel == 1) ? wk : wv;
    wT[(size_t)wsel * TH * TC + (size_t)h * TC + c] = (bf16)w[(size_t)c * TH + h];
}

// ---------------------------------------------------------------------------
// Kernel 1b: x fp32 -> xA bf16 in MFMA-fragment-major layout.
// xA[mt][kk][l16][8] : element (m,k) at ((mt*128+kk)*16+l16)*8 + j,
// mt=m/16, l16=m%16, kk=k/8, j=k%8. A wave's 16x32 A-frag for K-step s is
// the 1 KB contiguous block at ((mt*128 + s*4)*16)*8: lane(quad,l16) reads
// 16 B at + ((s*4+quad)*16+l16)*8. Writes below are gid*16B coalesced.
// ---------------------------------------------------------------------------
__launch_bounds__(256)
__global__ void xcvt(const float* __restrict__ x, bf16* __restrict__ xA) {
    const int gid = blockIdx.x * 256 + threadIdx.x;   // 2,097,152 threads
    const int l16 = gid & 15;
    const int kk  = (gid >> 4) & 127;
    const int mt  = gid >> 11;
    const float* xp = x + ((size_t)mt * 16 + l16) * TC + kk * 8;
    float4 a0 = ((const float4*)xp)[0];
    float4 a1 = ((const float4*)xp)[1];
    bf16x8 o;
    o[0] = (bf16)a0.x; o[1] = (bf16)a0.y; o[2] = (bf16)a0.z; o[3] = (bf16)a0.w;
    o[4] = (bf16)a1.x; o[5] = (bf16)a1.y; o[6] = (bf16)a1.z; o[7] = (bf16)a1.w;
    *(bf16x8*)(xA + (size_t)gid * 8) = o;
}

// ---------------------------------------------------------------------------
// Kernel 2: QKV projection. One wave = 16 rows x one of {Q,K,V}, full K=1024.
// A-frags: single contiguous 16B/lane load from xA (no LDS, no rings).
// B-frags: wT from L1/L2 (12 KB working set). 3072 waves = 12 waves/CU TLP.
// ---------------------------------------------------------------------------
__launch_bounds__(256, 2)
__global__ void gemm3(const bf16* __restrict__ xA, const bf16* __restrict__ wT,
                      bf16* __restrict__ Q, bf16* __restrict__ K, bf16* __restrict__ V) {
    const int wv   = threadIdx.x >> 6;
    const int lane = threadIdx.x & 63;
    const int quad = lane >> 4, l16 = lane & 15;
    const int gw   = blockIdx.x * 4 + wv;   // 0..3071
    const int wsel = gw % 3;                // trio sharing mt adjacent -> x L1/L2 reuse
    const int mt   = gw / 3;                // 0..1023

    const bf16* ap = xA + (((size_t)mt * 128 + quad) * 16 + l16) * 8;
    const bf16* wp = wT + (size_t)wsel * TH * TC + (size_t)l16 * TC + quad * 8;

    f32x4 acc[4];
#pragma unroll
    for (int g = 0; g < 4; g++) acc[g] = f32x4{0.f, 0.f, 0.f, 0.f};

#pragma unroll 4
    for (int s = 0; s < 32; s++) {
        bf16x8 af = *(const bf16x8*)(ap + (size_t)s * 512);
        const bf16* wps = wp + s * 32;
#pragma unroll
        for (int g = 0; g < 4; g++) {
            bf16x8 bq = *(const bf16x8*)(wps + (size_t)g * 16 * TC);
            acc[g] = __builtin_amdgcn_mfma_f32_16x16x32_bf16(af, bq, acc[g], 0, 0, 0);
        }
    }

    // epilogue: C layout row = quad*4+r, col = g*16+l16. V stored row-major.
    bf16* dst = (wsel == 0) ? Q : (wsel == 1) ? K : V;
    const float sc = (wsel == 0) ? QSCALE : 1.0f;
    const int mrow = mt * 16 + quad * 4;
#pragma unroll
    for (int g = 0; g < 4; g++) {
        int col = g * 16 + l16;
#pragma unroll
        for (int r = 0; r < 4; r++)
            dst[(size_t)(mrow + r) * TH + col] = (bf16)(acc[g][r] * sc);
    }
}

// ---------------------------------------------------------------------------
// Kernel 2b: V [B*T][64] -> VT [B][64][T]. Gather-read (L2-hot), coalesced store.
// ---------------------------------------------------------------------------
__launch_bounds__(256)
__global__ void vtrans(const bf16* __restrict__ V, bf16* __restrict__ VT) {
    const int gid = blockIdx.x * 256 + threadIdx.x;
    const int ts = gid & 255;          // 8-elem t segment
    const int h  = (gid >> 8) & 63;
    const int b  = gid >> 14;
    const bf16* vp = V + ((size_t)b * TT + ts * 8) * TH + h;
    bf16x8 o;
#pragma unroll
    for (int i = 0; i < 8; i++) o[i] = vp[(size_t)i * TH];
    *(bf16x8*)(VT + ((size_t)b * TH + h) * TT + ts * 8) = o;
}

// ---------------------------------------------------------------------------
// Kernel 3: causal flash attention (unchanged).
// ---------------------------------------------------------------------------
#define LDP 72
#define NW 4

__launch_bounds__(256)
__global__ void attn(const bf16* __restrict__ Q, const bf16* __restrict__ K,
                     const bf16* __restrict__ VT, float* __restrict__ out) {
    __shared__ __align__(16) union SM {
        bf16 P[NW][2][16][LDP];
        struct { float O[NW][16][68]; float M[NW][16]; float L[NW][16]; } mg;
    } sm;

    const int tid  = threadIdx.x;
    const int wv   = tid >> 6;
    const int lane = tid & 63;
    const int quad = lane >> 4, l16 = lane & 15;
    const int b  = blockIdx.x & 7;
    const int rt = 127 - (blockIdx.x >> 3);
    const int q0 = rt * 16;
    const int ktmax = rt >> 2;

    const bf16* Qb = Q  + (size_t)b * TT * TH;
    const bf16* Kb = K  + (size_t)b * TT * TH;
    const bf16* Vb = VT + (size_t)b * TH * TT;

    bf16x8 bq0, bq1;
    {
        const bf16* qp = Qb + (size_t)(q0 + l16) * TH + quad * 8;
        bq0 = *(const bf16x8*)qp;
        bq1 = *(const bf16x8*)(qp + 32);
    }

    f32x4 accO[4];
#pragma unroll
    for (int g = 0; g < 4; g++) accO[g] = f32x4{0.f, 0.f, 0.f, 0.f};
    float mI = -1e30f, lI = 0.f;

    int nit = 0;
    for (int kt = wv; kt <= ktmax; kt += NW, nit++) {
        const int k0 = kt * 64;

        f32x4 s[4];
#pragma unroll
        for (int g = 0; g < 4; g++) {
            const bf16* kp = Kb + (size_t)(k0 + g * 16 + l16) * TH + quad * 8;
            bf16x8 ka0 = *(const bf16x8*)kp;
            bf16x8 ka1 = *(const bf16x8*)(kp + 32);
            f32x4 t = f32x4{0.f, 0.f, 0.f, 0.f};
            t = __builtin_amdgcn_mfma_f32_16x16x32_bf16(ka0, bq0, t, 0, 0, 0);
            t = __builtin_amdgcn_mfma_f32_16x16x32_bf16(ka1, bq1, t, 0, 0, 0);
            s[g] = t;
        }

        if (kt == ktmax) {
            const int qrel = ((rt & 3) << 4) + l16;
#pragma unroll
            for (int g = 0; g < 4; g++)
#pragma unroll
                for (int r = 0; r < 4; r++)
                    if (g * 16 + quad * 4 + r > qrel) s[g][r] = -3.0e38f;
        }

        float mx = s[0][0];
#pragma unroll
        for (int g = 0; g < 4; g++)
#pragma unroll
            for (int r = 0; r < 4; r++) mx = fmaxf(mx, s[g][r]);
        mx = fmaxf(mx, __shfl_xor(mx, 16));
        mx = fmaxf(mx, __shfl_xor(mx, 32));
        float mnew  = fmaxf(mI, mx);
        float alpha = exp2f(mI - mnew);
        mI = mnew;
        float rs = 0.f;
#pragma unroll
        for (int g = 0; g < 4; g++)
#pragma unroll
            for (int r = 0; r < 4; r++) {
                float p = exp2f(s[g][r] - mnew);
                s[g][r] = p;
                rs += p;
            }
        rs += __shfl_xor(rs, 16);
        rs += __shfl_xor(rs, 32);
        lI = lI * alpha + rs;

        float arow[4];
#pragma unroll
        for (int r = 0; r < 4; r++) arow[r] = __shfl(alpha, quad * 4 + r);
#pragma unroll
        for (int g = 0; g < 4; g++)
#pragma unroll
            for (int r = 0; r < 4; r++) accO[g][r] *= arow[r];

        const int par = nit & 1;
#pragma unroll
        for (int g = 0; g < 4; g++) {
            bf16x4 pk;
            pk[0] = (bf16)s[g][0]; pk[1] = (bf16)s[g][1];
            pk[2] = (bf16)s[g][2]; pk[3] = (bf16)s[g][3];
            *(bf16x4*)(&sm.P[wv][par][l16][g * 16 + quad * 4]) = pk;
        }
        __threadfence_block();

#pragma unroll
        for (int c = 0; c < 2; c++) {
            bf16x8 ap = *(const bf16x8*)(&sm.P[wv][par][l16][c * 32 + quad * 8]);
#pragma unroll
            for (int g = 0; g < 4; g++) {
                const bf16* vp = Vb + (size_t)(g * 16 + l16) * TT + k0 + c * 32 + quad * 8;
                bf16x8 bv = *(const bf16x8*)vp;
                accO[g] = __builtin_amdgcn_mfma_f32_16x16x32_bf16(ap, bv, accO[g], 0, 0, 0);
            }
        }
    }

    __syncthreads();
#pragma unroll
    for (int g = 0; g < 4; g++)
#pragma unroll
        for (int r = 0; r < 4; r++)
            sm.mg.O[wv][quad * 4 + r][g * 16 + l16] = accO[g][r];
    if (lane < 16) {
        sm.mg.M[wv][lane] = mI;
        sm.mg.L[wv][lane] = lI;
    }
    __syncthreads();

    {
        const int q = tid >> 4;
        const int h = (tid & 15) * 4;
        float gm = sm.mg.M[0][q];
#pragma unroll
        for (int w = 1; w < NW; w++) gm = fmaxf(gm, sm.mg.M[w][q]);
        float denom = 0.f, o0 = 0.f, o1 = 0.f, o2 = 0.f, o3 = 0.f;
#pragma unroll
        for (int w = 0; w < NW; w++) {
            float sc = exp2f(sm.mg.M[w][q] - gm);
            denom += sm.mg.L[w][q] * sc;
            o0 += sm.mg.O[w][q][h + 0] * sc;
            o1 += sm.mg.O[w][q][h + 1] * sc;
            o2 += sm.mg.O[w][q][h + 2] * sc;
            o3 += sm.mg.O[w][q][h + 3] * sc;
        }
        float inv = 1.f / denom;
        float4 res = make_float4(o0 * inv, o1 * inv, o2 * inv, o3 * inv);
        *(float4*)(out + ((size_t)b * TT + q0 + q) * TH + h) = res;
    }
}

// ---------------------------------------------------------------------------
extern "C" void kernel_launch(void* const* d_in, const int* in_sizes, int n_in,
                              void* d_out, int out_size, void* d_ws, size_t ws_size,
                              hipStream_t stream) {
    const float* x  = (const float*)d_in[0];
    const float* wq = (const float*)d_in[1];
    const float* wk = (const float*)d_in[2];
    const float* wv = (const float*)d_in[3];

    char* ws = (char*)d_ws;
    bf16*  wT = (bf16*)(ws);                        // 393,216 B
    bf16*  xA = (bf16*)(ws + 393216);               // 33,554,432 B
    bf16*  Q  = (bf16*)(ws + 33947648);             // 2 MB
    bf16*  K  = (bf16*)(ws + 36044800);             // 2 MB
    bf16*  V  = (bf16*)(ws + 38141952);             // 2 MB
    bf16*  VT = (bf16*)(ws + 40239104);             // 2 MB  (end ~40.4 MB)
    float* out = (float*)d_out;

    hipLaunchKernelGGL(prep_wT, dim3(768), dim3(256), 0, stream, wq, wk, wv, wT);
    hipLaunchKernelGGL(xcvt, dim3(8192), dim3(256), 0, stream, x, xA);
    hipLaunchKernelGGL(gemm3, dim3(768), dim3(256), 0, stream, xA, wT, Q, K, V);
    hipLaunchKernelGGL(vtrans, dim3(512), dim3(256), 0, stream, V, VT);
    hipLaunchKernelGGL(attn, dim3(TB * 128), dim3(256), 0, stream, Q, K, VT, out);
}

// Round 6
// 157.233 us; speedup vs baseline: 1.2791x; 1.2510x over previous
//
#include <hip/hip_runtime.h>
#include <hip/hip_bf16.h>
#include <cstdint>

#define TB 8
#define TT 2048
#define TC 1024
#define TH 64

typedef __bf16 bf16;
typedef __bf16 bf16x4 __attribute__((ext_vector_type(4)));
typedef __bf16 bf16x8 __attribute__((ext_vector_type(8)));
typedef float  f32x4  __attribute__((ext_vector_type(4)));

// softmax scale folded with log2(e): attn uses exp2 instead of exp
constexpr float QSCALE = 0.125f * 1.44269504088896340736f;

// async global->LDS, 16B per lane. Dest = wave-uniform base + lane*16 (m104).
__device__ __forceinline__ void gll16(const void* g, void* l) {
    __builtin_amdgcn_global_load_lds((const __attribute__((address_space(1))) unsigned int*)g,
                                     (__attribute__((address_space(3))) unsigned int*)l, 16, 0, 0);
}

// ---------------------------------------------------------------------------
// Kernel 1: transpose + cast weights: w_{q,k,v}[1024][64] fp32 -> wT[3][64][1024] bf16
// ---------------------------------------------------------------------------
__global__ void prep_wT(const float* __restrict__ wq, const float* __restrict__ wk,
                        const float* __restrict__ wv, bf16* __restrict__ wT) {
    int idx = blockIdx.x * blockDim.x + threadIdx.x;
    if (idx >= 3 * TH * TC) return;
    int wsel = idx / (TH * TC);
    int rem  = idx % (TH * TC);
    int c = rem / TH;
    int h = rem % TH;
    const float* w = (wsel == 0) ? wq : (wsel == 1) ? wk : wv;
    wT[(size_t)wsel * TH * TC + (size_t)h * TC + c] = (bf16)w[(size_t)c * TH + h];
}

// ---------------------------------------------------------------------------
// Kernel 2: QKV projection, m97 structure. Block = 64 rows x 64 cols (one of
// Q/K/V), 4 waves x 16 rows. K=1024 in 16 BK=64 steps, double-buffered LDS
// staged via global_load_lds (fire-and-forget: compiler CANNOT sink these —
// rounds 2-5 proved it serializes any register-destined prefetch, VGPR 28-96).
// x staged raw fp32 (cvt at LDS->reg); wT staged bf16. XOR-swizzled LDS:
//   X chunk(row, c16) at row*256 + (c16 ^ (row&15))*16   (c16 = k-16B-chunk)
//   W chunk(col, c16) at col*128 + (c16 ^ (col&7))*16
// satisfies both the lane-contiguous DMA constraint and uniform-bank reads.
// ---------------------------------------------------------------------------
__launch_bounds__(256)
__global__ void proj(const float* __restrict__ x, const bf16* __restrict__ wT,
                     bf16* __restrict__ Q, bf16* __restrict__ K, bf16* __restrict__ VT) {
    __shared__ __align__(16) char lds[49152];   // Xb[2][16KB] @0, Wb[2][8KB] @32768
    const int tid  = threadIdx.x;
    const int wv   = tid >> 6;
    const int lane = tid & 63;
    const int quad = lane >> 4, l16 = lane & 15;
    const int wsel = blockIdx.x % 3;            // trio adjacency -> x L2 reuse
    const int m0   = (blockIdx.x / 3) * 64;

    const float* xb = x  + (size_t)m0 * TC;
    const bf16*  wb = wT + (size_t)wsel * (TH * TC);

    f32x4 acc[4];
#pragma unroll
    for (int g = 0; g < 4; g++) acc[g] = f32x4{0.f, 0.f, 0.f, 0.f};

    const int lr16 = lane >> 4, lc16 = lane & 15;   // X staging: 4 rows/inst
    const int lr8  = lane >> 3, lc8  = lane & 7;    // W staging: 8 cols/inst

#define STAGE(kc, bb)                                                          \
    {                                                                          \
        _Pragma("unroll")                                                      \
        for (int i = 0; i < 4; i++) {                                          \
            int base_row = wv * 16 + i * 4;                                    \
            int row = base_row + lr16;                                         \
            int c = lc16 ^ (row & 15);                                         \
            gll16(xb + (size_t)row * TC + (kc) * 64 + c * 4,                   \
                  lds + (bb) * 16384 + base_row * 256);                        \
        }                                                                      \
        _Pragma("unroll")                                                      \
        for (int i = 0; i < 2; i++) {                                          \
            int base_col = i * 32 + wv * 8;                                    \
            int col = base_col + lr8;                                          \
            int c = lc8 ^ (col & 7);                                           \
            gll16(wb + (size_t)col * TC + (kc) * 64 + c * 8,                   \
                  lds + 32768 + (bb) * 8192 + base_col * 128);                 \
        }                                                                      \
    }

    STAGE(0, 0);
    for (int kc = 0; kc < 16; kc++) {
        const int cur = kc & 1;
        __syncthreads();                        // vmcnt(0) drain: staged data visible
        if (kc + 1 < 16) STAGE(kc + 1, cur ^ 1);
        const char* Xb = lds + cur * 16384;
        const char* Wb = lds + 32768 + cur * 8192;
        const int row = wv * 16 + l16;
#pragma unroll
        for (int s = 0; s < 2; s++) {
            int c1 = (s * 8 + 2 * quad) ^ l16;
            int c2 = (s * 8 + 2 * quad + 1) ^ l16;
            f32x4 a0 = *(const f32x4*)(Xb + row * 256 + c1 * 16);
            f32x4 a1 = *(const f32x4*)(Xb + row * 256 + c2 * 16);
            bf16x8 af;
            af[0] = (bf16)a0[0]; af[1] = (bf16)a0[1]; af[2] = (bf16)a0[2]; af[3] = (bf16)a0[3];
            af[4] = (bf16)a1[0]; af[5] = (bf16)a1[1]; af[6] = (bf16)a1[2]; af[7] = (bf16)a1[3];
#pragma unroll
            for (int g = 0; g < 4; g++) {
                int col = g * 16 + l16;
                int c = (s * 4 + quad) ^ (col & 7);
                bf16x8 bq = *(const bf16x8*)(Wb + col * 128 + c * 16);
                acc[g] = __builtin_amdgcn_mfma_f32_16x16x32_bf16(af, bq, acc[g], 0, 0, 0);
            }
        }
    }

    // epilogue: C layout row = quad*4+r, col = g*16+l16
    const int mrow = m0 + wv * 16 + quad * 4;
    if (wsel == 0) {
#pragma unroll
        for (int g = 0; g < 4; g++) {
            int col = g * 16 + l16;
#pragma unroll
            for (int r = 0; r < 4; r++)
                Q[(size_t)(mrow + r) * TH + col] = (bf16)(acc[g][r] * QSCALE);
        }
    } else if (wsel == 1) {
#pragma unroll
        for (int g = 0; g < 4; g++) {
            int col = g * 16 + l16;
#pragma unroll
            for (int r = 0; r < 4; r++)
                K[(size_t)(mrow + r) * TH + col] = (bf16)acc[g][r];
        }
    } else {
        // VT[b][col][t]; 64-row tiles never cross the 2048-row batch boundary
        const int b = m0 >> 11;
        const int t = mrow & 2047;
#pragma unroll
        for (int g = 0; g < 4; g++) {
            int col = g * 16 + l16;
            bf16x4 o;
#pragma unroll
            for (int r = 0; r < 4; r++) o[r] = (bf16)acc[g][r];
            *(bf16x4*)(VT + ((size_t)b * TH + col) * TT + t) = o;
        }
    }
}

// ---------------------------------------------------------------------------
// Kernel 3: causal flash attention (unchanged).
// ---------------------------------------------------------------------------
#define LDP 72
#define NW 4

__launch_bounds__(256)
__global__ void attn(const bf16* __restrict__ Q, const bf16* __restrict__ K,
                     const bf16* __restrict__ VT, float* __restrict__ out) {
    __shared__ __align__(16) union SM {
        bf16 P[NW][2][16][LDP];
        struct { float O[NW][16][68]; float M[NW][16]; float L[NW][16]; } mg;
    } sm;

    const int tid  = threadIdx.x;
    const int wv   = tid >> 6;
    const int lane = tid & 63;
    const int quad = lane >> 4, l16 = lane & 15;
    const int b  = blockIdx.x & 7;
    const int rt = 127 - (blockIdx.x >> 3);
    const int q0 = rt * 16;
    const int ktmax = rt >> 2;

    const bf16* Qb = Q  + (size_t)b * TT * TH;
    const bf16* Kb = K  + (size_t)b * TT * TH;
    const bf16* Vb = VT + (size_t)b * TH * TT;

    bf16x8 bq0, bq1;
    {
        const bf16* qp = Qb + (size_t)(q0 + l16) * TH + quad * 8;
        bq0 = *(const bf16x8*)qp;
        bq1 = *(const bf16x8*)(qp + 32);
    }

    f32x4 accO[4];
#pragma unroll
    for (int g = 0; g < 4; g++) accO[g] = f32x4{0.f, 0.f, 0.f, 0.f};
    float mI = -1e30f, lI = 0.f;

    int nit = 0;
    for (int kt = wv; kt <= ktmax; kt += NW, nit++) {
        const int k0 = kt * 64;

        f32x4 s[4];
#pragma unroll
        for (int g = 0; g < 4; g++) {
            const bf16* kp = Kb + (size_t)(k0 + g * 16 + l16) * TH + quad * 8;
            bf16x8 ka0 = *(const bf16x8*)kp;
            bf16x8 ka1 = *(const bf16x8*)(kp + 32);
            f32x4 t = f32x4{0.f, 0.f, 0.f, 0.f};
            t = __builtin_amdgcn_mfma_f32_16x16x32_bf16(ka0, bq0, t, 0, 0, 0);
            t = __builtin_amdgcn_mfma_f32_16x16x32_bf16(ka1, bq1, t, 0, 0, 0);
            s[g] = t;
        }

        if (kt == ktmax) {
            const int qrel = ((rt & 3) << 4) + l16;
#pragma unroll
            for (int g = 0; g < 4; g++)
#pragma unroll
                for (int r = 0; r < 4; r++)
                    if (g * 16 + quad * 4 + r > qrel) s[g][r] = -3.0e38f;
        }

        float mx = s[0][0];
#pragma unroll
        for (int g = 0; g < 4; g++)
#pragma unroll
            for (int r = 0; r < 4; r++) mx = fmaxf(mx, s[g][r]);
        mx = fmaxf(mx, __shfl_xor(mx, 16));
        mx = fmaxf(mx, __shfl_xor(mx, 32));
        float mnew  = fmaxf(mI, mx);
        float alpha = exp2f(mI - mnew);
        mI = mnew;
        float rs = 0.f;
#pragma unroll
        for (int g = 0; g < 4; g++)
#pragma unroll
            for (int r = 0; r < 4; r++) {
                float p = exp2f(s[g][r] - mnew);
                s[g][r] = p;
                rs += p;
            }
        rs += __shfl_xor(rs, 16);
        rs += __shfl_xor(rs, 32);
        lI = lI * alpha + rs;

        float arow[4];
#pragma unroll
        for (int r = 0; r < 4; r++) arow[r] = __shfl(alpha, quad * 4 + r);
#pragma unroll
        for (int g = 0; g < 4; g++)
#pragma unroll
            for (int r = 0; r < 4; r++) accO[g][r] *= arow[r];

        const int par = nit & 1;
#pragma unroll
        for (int g = 0; g < 4; g++) {
            bf16x4 pk;
            pk[0] = (bf16)s[g][0]; pk[1] = (bf16)s[g][1];
            pk[2] = (bf16)s[g][2]; pk[3] = (bf16)s[g][3];
            *(bf16x4*)(&sm.P[wv][par][l16][g * 16 + quad * 4]) = pk;
        }
        __threadfence_block();

#pragma unroll
        for (int c = 0; c < 2; c++) {
            bf16x8 ap = *(const bf16x8*)(&sm.P[wv][par][l16][c * 32 + quad * 8]);
#pragma unroll
            for (int g = 0; g < 4; g++) {
                const bf16* vp = Vb + (size_t)(g * 16 + l16) * TT + k0 + c * 32 + quad * 8;
                bf16x8 bv = *(const bf16x8*)vp;
                accO[g] = __builtin_amdgcn_mfma_f32_16x16x32_bf16(ap, bv, accO[g], 0, 0, 0);
            }
        }
    }

    __syncthreads();
#pragma unroll
    for (int g = 0; g < 4; g++)
#pragma unroll
        for (int r = 0; r < 4; r++)
            sm.mg.O[wv][quad * 4 + r][g * 16 + l16] = accO[g][r];
    if (lane < 16) {
        sm.mg.M[wv][lane] = mI;
        sm.mg.L[wv][lane] = lI;
    }
    __syncthreads();

    {
        const int q = tid >> 4;
        const int h = (tid & 15) * 4;
        float gm = sm.mg.M[0][q];
#pragma unroll
        for (int w = 1; w < NW; w++) gm = fmaxf(gm, sm.mg.M[w][q]);
        float denom = 0.f, o0 = 0.f, o1 = 0.f, o2 = 0.f, o3 = 0.f;
#pragma unroll
        for (int w = 0; w < NW; w++) {
            float sc = exp2f(sm.mg.M[w][q] - gm);
            denom += sm.mg.L[w][q] * sc;
            o0 += sm.mg.O[w][q][h + 0] * sc;
            o1 += sm.mg.O[w][q][h + 1] * sc;
            o2 += sm.mg.O[w][q][h + 2] * sc;
            o3 += sm.mg.O[w][q][h + 3] * sc;
        }
        float inv = 1.f / denom;
        float4 res = make_float4(o0 * inv, o1 * inv, o2 * inv, o3 * inv);
        *(float4*)(out + ((size_t)b * TT + q0 + q) * TH + h) = res;
    }
}

// ---------------------------------------------------------------------------
extern "C" void kernel_launch(void* const* d_in, const int* in_sizes, int n_in,
                              void* d_out, int out_size, void* d_ws, size_t ws_size,
                              hipStream_t stream) {
    const float* x  = (const float*)d_in[0];
    const float* wq = (const float*)d_in[1];
    const float* wk = (const float*)d_in[2];
    const float* wv = (const float*)d_in[3];

    char* ws = (char*)d_ws;
    bf16*  wT = (bf16*)(ws);                        // 393,216 B
    bf16*  Q  = (bf16*)(ws + 393216);               // 2 MB
    bf16*  K  = (bf16*)(ws + 2490368);               // 2 MB
    bf16*  VT = (bf16*)(ws + 4587520);               // 2 MB
    float* out = (float*)d_out;

    hipLaunchKernelGGL(prep_wT, dim3(768), dim3(256), 0, stream, wq, wk, wv, wT);
    hipLaunchKernelGGL(proj, dim3(768), dim3(256), 0, stream, x, wT, Q, K, VT);
    hipLaunchKernelGGL(attn, dim3(TB * 128), dim3(256), 0, stream, Q, K, VT, out);
}

// Round 7
// 139.057 us; speedup vs baseline: 1.4463x; 1.1307x over previous
//
#include <hip/hip_runtime.h>
#include <hip/hip_bf16.h>
#include <cstdint>

#define TB 8
#define TT 2048
#define TC 1024
#define TH 64

typedef __bf16 bf16;
typedef __bf16 bf16x2 __attribute__((ext_vector_type(2)));
typedef __bf16 bf16x4 __attribute__((ext_vector_type(4)));
typedef __bf16 bf16x8 __attribute__((ext_vector_type(8)));
typedef float  f32x4  __attribute__((ext_vector_type(4)));

// softmax scale folded with log2(e): attn uses exp2 instead of exp
constexpr float QSCALE = 0.125f * 1.44269504088896340736f;

// async global->LDS, 16B per lane. Dest = wave-uniform base + lane*16 (m104).
__device__ __forceinline__ void gll16(const void* g, void* l) {
    __builtin_amdgcn_global_load_lds((const __attribute__((address_space(1))) unsigned int*)g,
                                     (__attribute__((address_space(3))) unsigned int*)l, 16, 0, 0);
}

// gfx9 waitcnt encodings: vmcnt[5:4]@[15:14] vmcnt[3:0]@[3:0] expcnt@[6:4] lgkmcnt@[11:8]
#define WAIT_VM0()   __builtin_amdgcn_s_waitcnt(0x0F70)   // vmcnt(0) only
#define WAIT_LGKM0() __builtin_amdgcn_s_waitcnt(0xC07F)   // lgkmcnt(0) only

// ---------------------------------------------------------------------------
// Kernel 1: transpose + cast weights: w_{q,k,v}[1024][64] fp32 -> wT[3][64][1024] bf16
// ---------------------------------------------------------------------------
__global__ void prep_wT(const float* __restrict__ wq, const float* __restrict__ wk,
                        const float* __restrict__ wv, bf16* __restrict__ wT) {
    int idx = blockIdx.x * blockDim.x + threadIdx.x;
    if (idx >= 3 * TH * TC) return;
    int wsel = idx / (TH * TC);
    int rem  = idx % (TH * TC);
    int c = rem / TH;
    int h = rem % TH;
    const float* w = (wsel == 0) ? wq : (wsel == 1) ? wk : wv;
    wT[(size_t)wsel * TH * TC + (size_t)h * TC + c] = (bf16)w[(size_t)c * TH + h];
}

// ---------------------------------------------------------------------------
// Kernel 2: QKV projection (unchanged from round 6 — global_load_lds staged).
// ---------------------------------------------------------------------------
__launch_bounds__(256)
__global__ void proj(const float* __restrict__ x, const bf16* __restrict__ wT,
                     bf16* __restrict__ Q, bf16* __restrict__ K, bf16* __restrict__ VT) {
    __shared__ __align__(16) char lds[49152];   // Xb[2][16KB] @0, Wb[2][8KB] @32768
    const int tid  = threadIdx.x;
    const int wv   = tid >> 6;
    const int lane = tid & 63;
    const int quad = lane >> 4, l16 = lane & 15;
    const int wsel = blockIdx.x % 3;
    const int m0   = (blockIdx.x / 3) * 64;

    const float* xb = x  + (size_t)m0 * TC;
    const bf16*  wb = wT + (size_t)wsel * (TH * TC);

    f32x4 acc[4];
#pragma unroll
    for (int g = 0; g < 4; g++) acc[g] = f32x4{0.f, 0.f, 0.f, 0.f};

    const int lr16 = lane >> 4, lc16 = lane & 15;
    const int lr8  = lane >> 3, lc8  = lane & 7;

#define STAGE(kc, bb)                                                          \
    {                                                                          \
        _Pragma("unroll")                                                      \
        for (int i = 0; i < 4; i++) {                                          \
            int base_row = wv * 16 + i * 4;                                    \
            int row = base_row + lr16;                                         \
            int c = lc16 ^ (row & 15);                                         \
            gll16(xb + (size_t)row * TC + (kc) * 64 + c * 4,                   \
                  lds + (bb) * 16384 + base_row * 256);                        \
        }                                                                      \
        _Pragma("unroll")                                                      \
        for (int i = 0; i < 2; i++) {                                          \
            int base_col = i * 32 + wv * 8;                                    \
            int col = base_col + lr8;                                          \
            int c = lc8 ^ (col & 7);                                           \
            gll16(wb + (size_t)col * TC + (kc) * 64 + c * 8,                   \
                  lds + 32768 + (bb) * 8192 + base_col * 128);                 \
        }                                                                      \
    }

    STAGE(0, 0);
    for (int kc = 0; kc < 16; kc++) {
        const int cur = kc & 1;
        __syncthreads();
        if (kc + 1 < 16) STAGE(kc + 1, cur ^ 1);
        const char* Xb = lds + cur * 16384;
        const char* Wb = lds + 32768 + cur * 8192;
        const int row = wv * 16 + l16;
#pragma unroll
        for (int s = 0; s < 2; s++) {
            int c1 = (s * 8 + 2 * quad) ^ l16;
            int c2 = (s * 8 + 2 * quad + 1) ^ l16;
            f32x4 a0 = *(const f32x4*)(Xb + row * 256 + c1 * 16);
            f32x4 a1 = *(const f32x4*)(Xb + row * 256 + c2 * 16);
            bf16x8 af;
            af[0] = (bf16)a0[0]; af[1] = (bf16)a0[1]; af[2] = (bf16)a0[2]; af[3] = (bf16)a0[3];
            af[4] = (bf16)a1[0]; af[5] = (bf16)a1[1]; af[6] = (bf16)a1[2]; af[7] = (bf16)a1[3];
#pragma unroll
            for (int g = 0; g < 4; g++) {
                int col = g * 16 + l16;
                int c = (s * 4 + quad) ^ (col & 7);
                bf16x8 bq = *(const bf16x8*)(Wb + col * 128 + c * 16);
                acc[g] = __builtin_amdgcn_mfma_f32_16x16x32_bf16(af, bq, acc[g], 0, 0, 0);
            }
        }
    }

    const int mrow = m0 + wv * 16 + quad * 4;
    if (wsel == 0) {
#pragma unroll
        for (int g = 0; g < 4; g++) {
            int col = g * 16 + l16;
#pragma unroll
            for (int r = 0; r < 4; r++)
                Q[(size_t)(mrow + r) * TH + col] = (bf16)(acc[g][r] * QSCALE);
        }
    } else if (wsel == 1) {
#pragma unroll
        for (int g = 0; g < 4; g++) {
            int col = g * 16 + l16;
#pragma unroll
            for (int r = 0; r < 4; r++)
                K[(size_t)(mrow + r) * TH + col] = (bf16)acc[g][r];
        }
    } else {
        const int b = m0 >> 11;
        const int t = mrow & 2047;
#pragma unroll
        for (int g = 0; g < 4; g++) {
            int col = g * 16 + l16;
            bf16x4 o;
#pragma unroll
            for (int r = 0; r < 4; r++) o[r] = (bf16)acc[g][r];
            *(bf16x4*)(VT + ((size_t)b * TH + col) * TT + t) = o;
        }
    }
}
#undef STAGE

// ---------------------------------------------------------------------------
// Kernel 3: causal flash attention v3.
// Block = (b, 32 q-rows), 4 waves split k-tiles (stride 4), in-LDS merge.
// Per-wave K/VT tiles (64t x 64h / 64h x 64t, XOR-swizzled) staged single-
// buffered via global_load_lds: vmcnt(0) -> ds_read frags -> lgkmcnt(0) ->
// issue next DMA -> compute (register-only: MFMA + softmax + ds_bpermute
// P-transform; NO LDS-RAM ops, so nothing forces a drain of the in-flight DMA).
// ---------------------------------------------------------------------------
__device__ __forceinline__ float packbf(float a, float b) {
    union { bf16x2 h; float f; } u;
    u.h[0] = (bf16)a; u.h[1] = (bf16)b;
    return u.f;
}

__launch_bounds__(256, 2)
__global__ void attn(const bf16* __restrict__ Q, const bf16* __restrict__ K,
                     const bf16* __restrict__ VT, float* __restrict__ out) {
    __shared__ __align__(16) char lds[65536];   // [4 waves][K 8KB | V 8KB]; merge union after loop

    const int tid  = threadIdx.x;
    const int wv   = tid >> 6;
    const int lane = tid & 63;
    const int quad = lane >> 4, l16 = lane & 15;
    const int b  = blockIdx.x & 7;
    const int qc = 63 - (blockIdx.x >> 3);      // long blocks first
    const int q0 = qc * 32;
    const int ktd = qc >> 1;                    // diagonal k-tile index

    char* Kst = lds + wv * 16384;
    char* Vst = Kst + 8192;

    const bf16* Qb = Q  + (size_t)b * TT * TH;
    const bf16* Kb = K  + (size_t)b * TT * TH;
    const bf16* Vb = VT + (size_t)b * TH * TT;

    // Q fragments (B-operand): B[k=h][n=q], q = q0 + qg*16 + l16
    bf16x8 bq[2][2];
#pragma unroll
    for (int qg = 0; qg < 2; qg++)
#pragma unroll
        for (int kh = 0; kh < 2; kh++)
            bq[qg][kh] = *(const bf16x8*)(Qb + (size_t)(q0 + qg * 16 + l16) * TH + kh * 32 + quad * 8);

    f32x4 accO[2][4];
#pragma unroll
    for (int qg = 0; qg < 2; qg++)
#pragma unroll
        for (int g = 0; g < 4; g++) accO[qg][g] = f32x4{0.f, 0.f, 0.f, 0.f};
    float mI[2] = {-1e30f, -1e30f}, lI[2] = {0.f, 0.f};

    const int r8 = lane >> 3, c8 = lane & 7;
    const int src1 = (quad & 1) * 32 + l16;     // bpermute source lanes
    const int src2 = src1 + 16;

    // stage tile kt: K rows t (chunk XOR t&7), V rows h (chunk XOR h&7)
#define STAGEKV(kt_)                                                            \
    {                                                                           \
        const int k0_ = (kt_) * 64;                                             \
        _Pragma("unroll")                                                       \
        for (int i = 0; i < 8; i++) {                                           \
            int t = i * 8 + r8;                                                 \
            gll16((const char*)Kb + (size_t)(k0_ + t) * 128 + ((c8 ^ (t & 7)) << 4), \
                  Kst + i * 1024);                                              \
        }                                                                       \
        _Pragma("unroll")                                                       \
        for (int i = 0; i < 8; i++) {                                           \
            int h = i * 8 + r8;                                                 \
            gll16((const char*)Vb + ((size_t)h * TT + k0_) * 2 + ((c8 ^ (h & 7)) << 4), \
                  Vst + i * 1024);                                              \
        }                                                                       \
    }

    if (wv <= ktd) {
        STAGEKV(wv);
        for (int kt = wv; kt <= ktd; kt += 4) {
            WAIT_VM0();                          // staged tile landed in LDS
            bf16x8 ka[4][2], bv[4][2];
#pragma unroll
            for (int g = 0; g < 4; g++) {
                int t = g * 16 + l16;
                const char* kr = Kst + t * 128;
                ka[g][0] = *(const bf16x8*)(kr + ((quad ^ (t & 7)) << 4));
                ka[g][1] = *(const bf16x8*)(kr + (((4 + quad) ^ (t & 7)) << 4));
                const char* vr = Vst + t * 128;
                bv[g][0] = *(const bf16x8*)(vr + ((quad ^ (t & 7)) << 4));
                bv[g][1] = *(const bf16x8*)(vr + (((4 + quad) ^ (t & 7)) << 4));
            }
            WAIT_LGKM0();                        // frags in regs; buffer reusable
            if (kt + 4 <= ktd) STAGEKV(kt + 4);  // fire-and-forget next tile

            // St = K Q^T : s[qg][g] C-layout (t = g*16+quad*4+r, q = qg*16+l16)
            f32x4 s[2][4];
#pragma unroll
            for (int g = 0; g < 4; g++)
#pragma unroll
                for (int qg = 0; qg < 2; qg++) {
                    f32x4 t0 = f32x4{0.f, 0.f, 0.f, 0.f};
                    t0 = __builtin_amdgcn_mfma_f32_16x16x32_bf16(ka[g][0], bq[qg][0], t0, 0, 0, 0);
                    t0 = __builtin_amdgcn_mfma_f32_16x16x32_bf16(ka[g][1], bq[qg][1], t0, 0, 0, 0);
                    s[qg][g] = t0;
                }

            if (kt == ktd) {                     // causal mask on diagonal tile
#pragma unroll
                for (int qg = 0; qg < 2; qg++) {
                    const int qrel = ((qc & 1) << 5) + qg * 16 + l16;
#pragma unroll
                    for (int g = 0; g < 4; g++)
#pragma unroll
                        for (int r = 0; r < 4; r++)
                            if (g * 16 + quad * 4 + r > qrel) s[qg][g][r] = -3.0e38f;
                }
            }

            // online softmax per qg (rows = l16, t across regs + quad axis)
            float alpha[2];
#pragma unroll
            for (int qg = 0; qg < 2; qg++) {
                float m = s[qg][0][0];
#pragma unroll
                for (int g = 0; g < 4; g++)
#pragma unroll
                    for (int r = 0; r < 4; r++) m = fmaxf(m, s[qg][g][r]);
                m = fmaxf(m, __shfl_xor(m, 16));
                m = fmaxf(m, __shfl_xor(m, 32));
                float mnew = fmaxf(mI[qg], m);
                float a = __builtin_amdgcn_exp2f(mI[qg] - mnew);
                mI[qg] = mnew;
                float rs = 0.f;
#pragma unroll
                for (int g = 0; g < 4; g++)
#pragma unroll
                    for (int r = 0; r < 4; r++) {
                        float p = __builtin_amdgcn_exp2f(s[qg][g][r] - mnew);
                        s[qg][g][r] = p;
                        rs += p;
                    }
                rs += __shfl_xor(rs, 16);
                rs += __shfl_xor(rs, 32);
                lI[qg] = lI[qg] * a + rs;
                alpha[qg] = a;
            }
            // rescale accO (rows q = quad*4+r need alpha from lane quad*4+r)
#pragma unroll
            for (int qg = 0; qg < 2; qg++) {
                float ar[4];
#pragma unroll
                for (int r = 0; r < 4; r++) ar[r] = __shfl(alpha[qg], quad * 4 + r);
#pragma unroll
                for (int g = 0; g < 4; g++)
#pragma unroll
                    for (int r = 0; r < 4; r++) accO[qg][g][r] *= ar[r];
            }

            // pack P to bf16 pairs, then C->A transform via ds_bpermute
            float pk[2][4][2];
#pragma unroll
            for (int qg = 0; qg < 2; qg++)
#pragma unroll
                for (int g = 0; g < 4; g++) {
                    pk[qg][g][0] = packbf(s[qg][g][0], s[qg][g][1]);
                    pk[qg][g][1] = packbf(s[qg][g][2], s[qg][g][3]);
                }

#pragma unroll
            for (int c = 0; c < 2; c++) {
#pragma unroll
                for (int qg = 0; qg < 2; qg++) {
                    float A0p0 = __shfl(pk[qg][c * 2][0], src1);
                    float A0p1 = __shfl(pk[qg][c * 2][1], src1);
                    float B0p0 = __shfl(pk[qg][c * 2][0], src2);
                    float B0p1 = __shfl(pk[qg][c * 2][1], src2);
                    float A1p0 = __shfl(pk[qg][c * 2 + 1][0], src1);
                    float A1p1 = __shfl(pk[qg][c * 2 + 1][1], src1);
                    float B1p0 = __shfl(pk[qg][c * 2 + 1][0], src2);
                    float B1p1 = __shfl(pk[qg][c * 2 + 1][1], src2);
                    bool lo = quad < 2;
                    union { float4 f; bf16x8 v; } u;
                    u.f = make_float4(lo ? A0p0 : A1p0, lo ? A0p1 : A1p1,
                                      lo ? B0p0 : B1p0, lo ? B0p1 : B1p1);
#pragma unroll
                    for (int g = 0; g < 4; g++)
                        accO[qg][g] = __builtin_amdgcn_mfma_f32_16x16x32_bf16(u.v, bv[g][c], accO[qg][g], 0, 0, 0);
                }
            }
        }
    }
#undef STAGEKV

    // ---- merge 4 waves' partial (O, m, l) in LDS (staging region reused) ----
    __syncthreads();                             // all staging reads + DMA done
    float* Omg = (float*)lds;                    // [4][32][68]
    float* Mmg = (float*)(lds + 34816);          // [4][32]
    float* Lmg = (float*)(lds + 35328);          // [4][32]
#pragma unroll
    for (int qg = 0; qg < 2; qg++)
#pragma unroll
        for (int g = 0; g < 4; g++)
#pragma unroll
            for (int r = 0; r < 4; r++)
                Omg[(size_t)(wv * 32 + qg * 16 + quad * 4 + r) * 68 + g * 16 + l16] = accO[qg][g][r];
    if (quad == 0) {
#pragma unroll
        for (int qg = 0; qg < 2; qg++) {
            Mmg[wv * 32 + qg * 16 + l16] = mI[qg];
            Lmg[wv * 32 + qg * 16 + l16] = lI[qg];
        }
    }
    __syncthreads();

#pragma unroll
    for (int p = 0; p < 2; p++) {
        const int idx = p * 256 + tid;
        const int q = idx >> 4;
        const int hs = (idx & 15) * 4;
        float gm = Mmg[q];
#pragma unroll
        for (int w = 1; w < 4; w++) gm = fmaxf(gm, Mmg[w * 32 + q]);
        float denom = 0.f, o0 = 0.f, o1 = 0.f, o2 = 0.f, o3 = 0.f;
#pragma unroll
        for (int w = 0; w < 4; w++) {
            float sc = __builtin_amdgcn_exp2f(Mmg[w * 32 + q] - gm);
            denom += Lmg[w * 32 + q] * sc;
            const float* op = Omg + (size_t)(w * 32 + q) * 68 + hs;
            o0 += op[0] * sc; o1 += op[1] * sc; o2 += op[2] * sc; o3 += op[3] * sc;
        }
        float inv = 1.f / denom;
        *(float4*)(out + ((size_t)b * TT + q0 + q) * TH + hs) =
            make_float4(o0 * inv, o1 * inv, o2 * inv, o3 * inv);
    }
}

// ---------------------------------------------------------------------------
extern "C" void kernel_launch(void* const* d_in, const int* in_sizes, int n_in,
                              void* d_out, int out_size, void* d_ws, size_t ws_size,
                              hipStream_t stream) {
    const float* x  = (const float*)d_in[0];
    const float* wq = (const float*)d_in[1];
    const float* wk = (const float*)d_in[2];
    const float* wv = (const float*)d_in[3];

    char* ws = (char*)d_ws;
    bf16*  wT = (bf16*)(ws);                        // 393,216 B
    bf16*  Q  = (bf16*)(ws + 393216);               // 2 MB
    bf16*  K  = (bf16*)(ws + 2490368);              // 2 MB
    bf16*  VT = (bf16*)(ws + 4587520);              // 2 MB
    float* out = (float*)d_out;

    hipLaunchKernelGGL(prep_wT, dim3(768), dim3(256), 0, stream, wq, wk, wv, wT);
    hipLaunchKernelGGL(proj, dim3(768), dim3(256), 0, stream, x, wT, Q, K, VT);
    hipLaunchKernelGGL(attn, dim3(TB * 64), dim3(256), 0, stream, Q, K, VT, out);
}